// Round 2
// baseline (871.796 us; speedup 1.0000x reference)
//
#include <hip/hip_runtime.h>
#include <math.h>

#define BB 16
#define HH 32
#define KVHH 8
#define GG 4
#define DD 128
#define SS 4096
#define PGROUPS 64              // split-S partials per (b, kvh)
#define SPAN (SS / PGROUPS)     // 64 positions per span
#define PSTRIDE (GG * DD + 2 * GG)  // 520 floats: acc[4][128], m[4], l[4]
#define UCH 4                   // positions per chunk (MLP depth)
// SCALE * log2(e): fold softmax base-2 conversion into the q coefficients
#define S2C 0.12751744f

__device__ __forceinline__ float vget(const float4& v, int i) {
  return (&v.x)[i];
}

// Kernel 1: split-S flash-decoding partials.
// grid = B * PGROUPS blocks; block = 256 = 8 groups of 32 lanes.
// Group g handles kv-head g over the block's span => slot/pos loads are
// block-uniform (scalar loads), no intra-wave divergence.
__global__ __launch_bounds__(256) void pa_split(
    const float* __restrict__ q,
    const float* __restrict__ kc,
    const float* __restrict__ vc,
    const int* __restrict__ slots,
    const int* __restrict__ positions,
    const int* __restrict__ ctxlen,
    float* __restrict__ part)
{
  const int b    = blockIdx.x >> 6;   // PGROUPS = 64
  const int p    = blockIdx.x & 63;
  const int tid  = threadIdx.x;
  const int lane = tid & 31;
  const int kvh  = tid >> 5;          // 0..7
  const int s0   = p * SPAN;
  const int ctx  = ctxlen[b];
  int nvalid = ctx - s0;
  nvalid = nvalid < 0 ? 0 : (nvalid > SPAN ? SPAN : nvalid);

  const int d0 = lane * 4;
  float* pb = part + (((size_t)b * KVHH + kvh) * PGROUPS + p) * PSTRIDE;

  if (nvalid == 0) {   // uniform across block
    #pragma unroll
    for (int g = 0; g < GG; ++g)
      *(float4*)(pb + g * DD + d0) = make_float4(0.f, 0.f, 0.f, 0.f);
    if (lane == 0) {
      #pragma unroll
      for (int g = 0; g < GG; ++g) {
        pb[GG * DD + g]      = -1e30f;
        pb[GG * DD + GG + g] = 0.f;
      }
    }
    return;
  }

  // inv_freq for this lane's 4 d-values: 10000^(-j/64), j = d & 63
  float invf[4];
  #pragma unroll
  for (int i = 0; i < 4; ++i) {
    int j = (d0 + i) & 63;
    invf[i] = __expf(-0.14391157f * (float)j);  // ln(10000)/64
  }

  // ---- one-time q setup: rope, then move K-side rope to q coefficients ----
  // score(pos_k) = sum_f K_f * (Qc_f * cos_f(pos_k) + Qs_f * sin_f(pos_k))
  // Qc_f = Qr_f, Qs_f = tau_f * Qr_{f^64}, tau = +1 (f<64) / -1 (f>=64).
  const int pos_last = positions[b * SS + (ctx - 1)];
  float Qc[GG][4], Qs[GG][4];
  {
    float qsn[4], qcs[4];
    #pragma unroll
    for (int i = 0; i < 4; ++i)
      __sincosf((float)pos_last * invf[i], &qsn[i], &qcs[i]);
    const float tau = (lane < 16) ? 1.f : -1.f;
    #pragma unroll
    for (int g = 0; g < GG; ++g) {
      const float4 x4 = *(const float4*)(q + ((size_t)b * HH + kvh * GG + g) * DD + d0);
      const float x[4] = {x4.x, x4.y, x4.z, x4.w};
      #pragma unroll
      for (int i = 0; i < 4; ++i) {
        float px = __shfl_xor(x[i], 16, 32);        // q_{f^64}
        float r  = (lane < 16) ? -px : px;
        float Qr = x[i] * qcs[i] + r * qsn[i];      // roped q
        float Qp = __shfl_xor(Qr, 16, 32);          // roped q partner
        Qc[g][i] = Qr * S2C;
        Qs[g][i] = tau * Qp * S2C;
      }
    }
  }

  const int sb = b * SS + s0;

  auto load_chunk = [&](int base, float4 kb[UCH], float4 vb[UCH], int pn[UCH]) {
    #pragma unroll
    for (int u = 0; u < UCH; ++u) {
      int idx = base + u;
      idx = (idx > nvalid - 1) ? (nvalid - 1) : idx;  // clamp tail (masked later)
      const int slot = slots[sb + idx];               // block-uniform -> s_load
      pn[u] = positions[sb + idx];
      const size_t off = ((size_t)slot * KVHH + kvh) * DD + d0;
      kb[u] = *(const float4*)(kc + off);
      vb[u] = *(const float4*)(vc + off);
    }
  };

  float m2[GG], l[GG], acc[GG][4];
  #pragma unroll
  for (int g = 0; g < GG; ++g) {
    m2[g] = -1e30f; l[g] = 0.f;
    #pragma unroll
    for (int i = 0; i < 4; ++i) acc[g][i] = 0.f;
  }

  float4 kb[UCH], vb[UCH]; int pn[UCH];
  load_chunk(0, kb, vb, pn);
  const int nch = (nvalid + UCH - 1) / UCH;

  for (int c = 0; c < nch; ++c) {
    float4 kn[UCH], vn[UCH]; int pnn[UCH];
    const bool more = (c + 1 < nch);
    if (more) load_chunk((c + 1) * UCH, kn, vn, pnn);   // prefetch next chunk

    const int base = c * UCH;
    float sc[GG][UCH];
    #pragma unroll
    for (int u = 0; u < UCH; ++u) {
      float sn[4], cs[4];
      const float fp = (float)pn[u];
      #pragma unroll
      for (int i = 0; i < 4; ++i)
        __sincosf(fp * invf[i], &sn[i], &cs[i]);
      float kcv[4], ksv[4];
      #pragma unroll
      for (int i = 0; i < 4; ++i) {
        const float kx = vget(kb[u], i);
        kcv[i] = kx * cs[i];
        ksv[i] = kx * sn[i];
      }
      #pragma unroll
      for (int g = 0; g < GG; ++g) {
        float s = 0.f;
        #pragma unroll
        for (int i = 0; i < 4; ++i)
          s += Qc[g][i] * kcv[i] + Qs[g][i] * ksv[i];
        sc[g][u] = s;
      }
    }

    // 32-lane reduction of 16 scores
    #pragma unroll
    for (int off = 16; off > 0; off >>= 1) {
      #pragma unroll
      for (int g = 0; g < GG; ++g) {
        #pragma unroll
        for (int u = 0; u < UCH; ++u)
          sc[g][u] += __shfl_xor(sc[g][u], off, 32);
      }
    }

    // mask tail positions
    #pragma unroll
    for (int u = 0; u < UCH; ++u) {
      if (base + u >= nvalid) {
        #pragma unroll
        for (int g = 0; g < GG; ++g) sc[g][u] = -1e30f;
      }
    }

    // online softmax (base-2), chunk-granular rescale
    #pragma unroll
    for (int g = 0; g < GG; ++g) {
      const float cmax = fmaxf(fmaxf(sc[g][0], sc[g][1]), fmaxf(sc[g][2], sc[g][3]));
      const float mn   = fmaxf(m2[g], cmax);
      const float corr = __builtin_exp2f(m2[g] - mn);
      m2[g] = mn;
      float pw[UCH];
      #pragma unroll
      for (int u = 0; u < UCH; ++u)
        pw[u] = __builtin_exp2f(sc[g][u] - mn);
      l[g] = l[g] * corr + (pw[0] + pw[1]) + (pw[2] + pw[3]);
      #pragma unroll
      for (int i = 0; i < 4; ++i) {
        const float vsum = pw[0] * vget(vb[0], i) + pw[1] * vget(vb[1], i)
                         + pw[2] * vget(vb[2], i) + pw[3] * vget(vb[3], i);
        acc[g][i] = acc[g][i] * corr + vsum;
      }
    }

    if (more) {
      #pragma unroll
      for (int u = 0; u < UCH; ++u) { kb[u] = kn[u]; vb[u] = vn[u]; pn[u] = pnn[u]; }
    }
  }

  // write partial state (m/l are in base-2 space)
  #pragma unroll
  for (int g = 0; g < GG; ++g)
    *(float4*)(pb + g * DD + d0) =
        make_float4(acc[g][0], acc[g][1], acc[g][2], acc[g][3]);
  if (lane == 0) {
    #pragma unroll
    for (int g = 0; g < GG; ++g) {
      pb[GG * DD + g]      = m2[g];
      pb[GG * DD + GG + g] = l[g];
    }
  }
}

// Kernel 2: combine 64 partials per (b, h). grid = B*H, block = 128.
__global__ __launch_bounds__(128) void pa_combine(
    const float* __restrict__ part, float* __restrict__ out)
{
  const int bh  = blockIdx.x;      // 0..511
  const int b   = bh >> 5;
  const int h   = bh & 31;
  const int kvh = h >> 2;
  const int g   = h & 3;
  const int d   = threadIdx.x;

  const float* pbase = part + ((size_t)(b * KVHH + kvh)) * PGROUPS * PSTRIDE;
  float M = -1e30f, L = 0.f, o = 0.f;
  for (int p = 0; p < PGROUPS; ++p) {
    const float* pp = pbase + (size_t)p * PSTRIDE;
    float mp = pp[GG * DD + g];
    float lp = pp[GG * DD + GG + g];
    float a  = pp[g * DD + d];
    float Mn = fmaxf(M, mp);
    float e0 = __builtin_exp2f(M - Mn);
    float e1 = __builtin_exp2f(mp - Mn);
    o = o * e0 + a * e1;
    L = L * e0 + lp * e1;
    M = Mn;
  }
  out[((size_t)b * HH + h) * DD + d] = o / L;
}

extern "C" void kernel_launch(void* const* d_in, const int* in_sizes, int n_in,
                              void* d_out, int out_size, void* d_ws, size_t ws_size,
                              hipStream_t stream) {
  const float* q_p   = (const float*)d_in[0];
  const float* kc_p  = (const float*)d_in[1];
  const float* vc_p  = (const float*)d_in[2];
  const int*   slots = (const int*)d_in[3];
  const int*   poss  = (const int*)d_in[4];
  const int*   ctxl  = (const int*)d_in[5];
  float* part = (float*)d_ws;   // B*KVH*PGROUPS*PSTRIDE*4 ~= 17 MB
  float* outp = (float*)d_out;

  pa_split<<<BB * PGROUPS, 256, 0, stream>>>(
      q_p, kc_p, vc_p, slots, poss, ctxl, part);
  pa_combine<<<BB * HH, 128, 0, stream>>>(part, outp);
}